// Round 4
// baseline (1133.521 us; speedup 1.0000x reference)
//
#include <hip/hip_runtime.h>

#define USER_NUM 100000
#define ITEM_NUM 50000
#define N_NODES  150000   // USER_NUM + ITEM_NUM
#define EMB_DIM  64
#define NNZ      4800000
#define N_VEC4   (N_NODES * (EMB_DIM / 4))   // 2.4M float4 elements

#define SCAN_ITEMS 1024
#define NUM_SCAN_BLOCKS ((N_NODES + SCAN_ITEMS - 1) / SCAN_ITEMS)  // 147

// ---------------------------------------------------------------------------
// init: ego = concat(user_emb, item_emb); acc (= d_out) = ego
// ---------------------------------------------------------------------------
__global__ void lgcn_init(const float4* __restrict__ user,
                          const float4* __restrict__ item,
                          float4* __restrict__ ego,
                          float4* __restrict__ acc) {
    int i = blockIdx.x * blockDim.x + threadIdx.x;
    if (i >= N_VEC4) return;
    const int user_elems = USER_NUM * (EMB_DIM / 4);
    float4 v = (i < user_elems) ? user[i] : item[i - user_elems];
    ego[i] = v;
    acc[i] = v;
}

// ---------------------------------------------------------------------------
// CSR build step 1: histogram of row indices
// ---------------------------------------------------------------------------
__global__ void lgcn_hist(const int* __restrict__ row, int* __restrict__ cnt) {
    int e = blockIdx.x * blockDim.x + threadIdx.x;
    if (e >= NNZ) return;
    atomicAdd(&cnt[row[e]], 1);
}

// ---------------------------------------------------------------------------
// CSR build step 2a: per-block sums of cnt (1024 elements / block)
// ---------------------------------------------------------------------------
__global__ void lgcn_scan_blocksums(const int* __restrict__ cnt,
                                    int* __restrict__ blockSum) {
    int b = blockIdx.x, t = threadIdx.x;
    int base = b * SCAN_ITEMS + t * 4;
    int s = 0;
#pragma unroll
    for (int k = 0; k < 4; ++k) {
        int i = base + k;
        if (i < N_NODES) s += cnt[i];
    }
    __shared__ int red[256];
    red[t] = s;
    __syncthreads();
    for (int off = 128; off > 0; off >>= 1) {
        if (t < off) red[t] += red[t + off];
        __syncthreads();
    }
    if (t == 0) blockSum[b] = red[0];
}

// ---------------------------------------------------------------------------
// CSR build step 2b: exclusive scan of block sums (single block)
// ---------------------------------------------------------------------------
__global__ void lgcn_scan_sums(const int* __restrict__ blockSum,
                               int* __restrict__ blockBase,
                               int* __restrict__ row_ptr) {
    int t = threadIdx.x;
    __shared__ int s[256];
    int v = (t < NUM_SCAN_BLOCKS) ? blockSum[t] : 0;
    s[t] = v;
    __syncthreads();
    for (int off = 1; off < 256; off <<= 1) {
        int x = (t >= off) ? s[t - off] : 0;
        __syncthreads();
        s[t] += x;
        __syncthreads();
    }
    if (t < NUM_SCAN_BLOCKS) blockBase[t] = s[t] - v;  // exclusive
    if (t == 0) row_ptr[N_NODES] = NNZ;
}

// ---------------------------------------------------------------------------
// CSR build step 2c: final exclusive scan -> row_ptr[0..N_NODES)
// ---------------------------------------------------------------------------
__global__ void lgcn_scan_final(const int* __restrict__ cnt,
                                const int* __restrict__ blockBase,
                                int* __restrict__ row_ptr) {
    int b = blockIdx.x, t = threadIdx.x;
    int base = b * SCAN_ITEMS + t * 4;
    int v[4];
    int tsum = 0;
#pragma unroll
    for (int k = 0; k < 4; ++k) {
        int i = base + k;
        v[k] = (i < N_NODES) ? cnt[i] : 0;
        tsum += v[k];
    }
    __shared__ int s[256];
    s[t] = tsum;
    __syncthreads();
    for (int off = 1; off < 256; off <<= 1) {
        int x = (t >= off) ? s[t - off] : 0;
        __syncthreads();
        s[t] += x;
        __syncthreads();
    }
    int p = blockBase[b] + (s[t] - tsum);  // exclusive prefix for this thread
#pragma unroll
    for (int k = 0; k < 4; ++k) {
        int i = base + k;
        if (i < N_NODES) row_ptr[i] = p;
        p += v[k];
    }
}

// ---------------------------------------------------------------------------
// CSR build step 3: scatter (col, val) into CSR order — packed 8B nontemporal
// store (bypass L2 line allocation for the random-position write)
// ---------------------------------------------------------------------------
__global__ void lgcn_scatter(const int* __restrict__ row,
                             const int* __restrict__ col,
                             const float* __restrict__ vals,
                             const int* __restrict__ row_ptr,
                             int* __restrict__ cursor,
                             unsigned long long* __restrict__ csr_cv) {
    int e = blockIdx.x * blockDim.x + threadIdx.x;
    if (e >= NNZ) return;
    int r = row[e];
    int pos = row_ptr[r] + atomicAdd(&cursor[r], 1);
    unsigned long long packed =
        (unsigned long long)(unsigned)col[e] |
        ((unsigned long long)(unsigned)__float_as_uint(vals[e]) << 32);
    __builtin_nontemporal_store(packed, &csr_cv[pos]);
}

// ---------------------------------------------------------------------------
// SpMM (pure gather): one wave per row. Lanes = 4 edge-subgroups x 16 chunks.
// Edge loop unrolled x4: 4 independent cv loads then 4 independent 256B
// x-gathers in flight per wave iteration. Fused epilogue:
// y = A@x row; acc = (acc + y) * scale.
// ---------------------------------------------------------------------------
__global__ __launch_bounds__(256) void lgcn_spmm_csr(
    const int* __restrict__ row_ptr,
    const int2* __restrict__ csr_cv,
    const float* __restrict__ x,
    float4* __restrict__ y,
    float4* __restrict__ acc,
    float scale) {
    int gid = blockIdx.x * blockDim.x + threadIdx.x;
    int r = gid >> 6;
    if (r >= N_NODES) return;
    int lane = threadIdx.x & 63;
    int chunk = lane & 15;   // which float4 of the 64-dim row
    int sub = lane >> 4;     // edge subgroup 0..3

    int start = row_ptr[r];
    int end = row_ptr[r + 1];

    float4 a0 = make_float4(0.f, 0.f, 0.f, 0.f);
    float4 a1 = make_float4(0.f, 0.f, 0.f, 0.f);
    float4 a2 = make_float4(0.f, 0.f, 0.f, 0.f);
    float4 a3 = make_float4(0.f, 0.f, 0.f, 0.f);
    const float4* x4 = (const float4*)x;

    int e = start + sub;
    // main loop: 16 edges per wave iteration (4 per subgroup)
    for (; e + 12 < end; e += 16) {
        int2 cv0 = csr_cv[e];
        int2 cv1 = csr_cv[e + 4];
        int2 cv2 = csr_cv[e + 8];
        int2 cv3 = csr_cv[e + 12];
        float4 x0 = x4[cv0.x * 16 + chunk];
        float4 x1 = x4[cv1.x * 16 + chunk];
        float4 x2 = x4[cv2.x * 16 + chunk];
        float4 x3 = x4[cv3.x * 16 + chunk];
        float v0 = __int_as_float(cv0.y);
        float v1 = __int_as_float(cv1.y);
        float v2 = __int_as_float(cv2.y);
        float v3 = __int_as_float(cv3.y);
        a0.x += v0 * x0.x; a0.y += v0 * x0.y; a0.z += v0 * x0.z; a0.w += v0 * x0.w;
        a1.x += v1 * x1.x; a1.y += v1 * x1.y; a1.z += v1 * x1.z; a1.w += v1 * x1.w;
        a2.x += v2 * x2.x; a2.y += v2 * x2.y; a2.z += v2 * x2.z; a2.w += v2 * x2.w;
        a3.x += v3 * x3.x; a3.y += v3 * x3.y; a3.z += v3 * x3.z; a3.w += v3 * x3.w;
    }
    // tail: up to 3 more edges per subgroup
    for (; e < end; e += 4) {
        int2 cv = csr_cv[e];
        float v = __int_as_float(cv.y);
        float4 xv = x4[cv.x * 16 + chunk];
        a0.x += v * xv.x; a0.y += v * xv.y; a0.z += v * xv.z; a0.w += v * xv.w;
    }
    float4 a;
    a.x = (a0.x + a1.x) + (a2.x + a3.x);
    a.y = (a0.y + a1.y) + (a2.y + a3.y);
    a.z = (a0.z + a1.z) + (a2.z + a3.z);
    a.w = (a0.w + a1.w) + (a2.w + a3.w);

    // reduce across the 4 edge subgroups (lanes differing in bits 4,5)
    a.x += __shfl_xor(a.x, 16); a.y += __shfl_xor(a.y, 16);
    a.z += __shfl_xor(a.z, 16); a.w += __shfl_xor(a.w, 16);
    a.x += __shfl_xor(a.x, 32); a.y += __shfl_xor(a.y, 32);
    a.z += __shfl_xor(a.z, 32); a.w += __shfl_xor(a.w, 32);

    if (sub == 0) {
        int idx = r * 16 + chunk;
        y[idx] = a;
        float4 o = acc[idx];
        o.x = (o.x + a.x) * scale;
        o.y = (o.y + a.y) * scale;
        o.z = (o.z + a.z) * scale;
        o.w = (o.w + a.w) * scale;
        acc[idx] = o;
    }
}

extern "C" void kernel_launch(void* const* d_in, const int* in_sizes, int n_in,
                              void* d_out, int out_size, void* d_ws, size_t ws_size,
                              hipStream_t stream) {
    const float* user_emb = (const float*)d_in[0];
    const float* item_emb = (const float*)d_in[1];
    const int*   adj_row  = (const int*)d_in[2];
    const int*   adj_col  = (const int*)d_in[3];
    const float* adj_vals = (const float*)d_in[4];
    float* out = (float*)d_out;

    // workspace layout (~116.4 MB total)
    float* ego_a   = (float*)d_ws;                       // 38.4 MB
    float* ego_b   = ego_a + (size_t)N_NODES * EMB_DIM;  // 38.4 MB
    int*   cnt     = (int*)(ego_b + (size_t)N_NODES * EMB_DIM);  // 600 KB
    int*   row_ptr = cnt + N_NODES;                      // 600 KB
    int*   blockSum  = row_ptr + (N_NODES + 1);          // 1 KB
    int*   blockBase = blockSum + 256;                   // 1 KB
    int2*  csr_cv  = (int2*)(blockBase + 256);           // 38.4 MB interleaved

    // init: ego_a = concat(user,item); out (acc) = same
    {
        int threads = 256;
        int blocks = (N_VEC4 + threads - 1) / threads;
        lgcn_init<<<blocks, threads, 0, stream>>>(
            (const float4*)user_emb, (const float4*)item_emb,
            (float4*)ego_a, (float4*)out);
    }

    // ---- CSR build ----
    hipMemsetAsync(cnt, 0, (size_t)N_NODES * sizeof(int), stream);
    {
        int threads = 256;
        int blocks = (NNZ + threads - 1) / threads;
        lgcn_hist<<<blocks, threads, 0, stream>>>(adj_row, cnt);
    }
    lgcn_scan_blocksums<<<NUM_SCAN_BLOCKS, 256, 0, stream>>>(cnt, blockSum);
    lgcn_scan_sums<<<1, 256, 0, stream>>>(blockSum, blockBase, row_ptr);
    lgcn_scan_final<<<NUM_SCAN_BLOCKS, 256, 0, stream>>>(cnt, blockBase, row_ptr);
    hipMemsetAsync(cnt, 0, (size_t)N_NODES * sizeof(int), stream);  // reuse as cursor
    {
        int threads = 256;
        int blocks = (NNZ + threads - 1) / threads;
        lgcn_scatter<<<blocks, threads, 0, stream>>>(
            adj_row, adj_col, adj_vals, row_ptr, cnt,
            (unsigned long long*)csr_cv);
    }

    // ---- 3 propagation layers (pure-gather SpMM, fused acc update) ----
    const int spmm_block = 256;                       // 4 waves = 4 rows / block
    const int spmm_grid = (N_NODES * 64 + spmm_block - 1) / spmm_block;
    for (int layer = 0; layer < 3; ++layer) {
        float scale = (layer == 2) ? 0.25f : 1.0f;
        lgcn_spmm_csr<<<spmm_grid, spmm_block, 0, stream>>>(
            row_ptr, csr_cv, ego_a,
            (float4*)ego_b, (float4*)out, scale);
        float* t = ego_a; ego_a = ego_b; ego_b = t;
    }
}

// Round 5
// 875.230 us; speedup vs baseline: 1.2951x; 1.2951x over previous
//
#include <hip/hip_runtime.h>

#define USER_NUM 100000
#define ITEM_NUM 50000
#define N_NODES  150000   // USER_NUM + ITEM_NUM
#define EMB_DIM  64
#define NNZ      4800000
#define N_VEC4   (N_NODES * (EMB_DIM / 4))   // 2.4M float4 elements

#define SCAN_ITEMS 1024
#define NUM_SCAN_BLOCKS ((N_NODES + SCAN_ITEMS - 1) / SCAN_ITEMS)  // 147

// bf16 helpers: unpack a uint32 holding two bf16 (low ushort = even elem)
__device__ __forceinline__ float bflo(unsigned u) {
    return __uint_as_float(u << 16);
}
__device__ __forceinline__ float bfhi(unsigned u) {
    return __uint_as_float(u & 0xFFFF0000u);
}
// fp32 -> bf16 (RNE), returned in low 16 bits
__device__ __forceinline__ unsigned f2bf(float f) {
    unsigned u = __float_as_uint(f);
    return (u + 0x7FFFu + ((u >> 16) & 1u)) >> 16;
}

// ---------------------------------------------------------------------------
// init: acc (= d_out) = concat(user_emb, item_emb) fp32;
//       xb = same, packed bf16 (8 elems = uint4 per thread)
// ---------------------------------------------------------------------------
__global__ void lgcn_init(const float4* __restrict__ user,
                          const float4* __restrict__ item,
                          uint4* __restrict__ xb,
                          float4* __restrict__ acc) {
    int i = blockIdx.x * blockDim.x + threadIdx.x;   // chunk of 8 floats
    if (i >= N_NODES * 8) return;
    const int user_chunks = USER_NUM * 8;
    float4 f0, f1;
    if (i < user_chunks) {
        f0 = user[i * 2];
        f1 = user[i * 2 + 1];
    } else {
        f0 = item[(i - user_chunks) * 2];
        f1 = item[(i - user_chunks) * 2 + 1];
    }
    acc[i * 2]     = f0;
    acc[i * 2 + 1] = f1;
    uint4 p;
    p.x = f2bf(f0.x) | (f2bf(f0.y) << 16);
    p.y = f2bf(f0.z) | (f2bf(f0.w) << 16);
    p.z = f2bf(f1.x) | (f2bf(f1.y) << 16);
    p.w = f2bf(f1.z) | (f2bf(f1.w) << 16);
    xb[i] = p;
}

// ---------------------------------------------------------------------------
// CSR build step 1: histogram of row indices
// ---------------------------------------------------------------------------
__global__ void lgcn_hist(const int* __restrict__ row, int* __restrict__ cnt) {
    int e = blockIdx.x * blockDim.x + threadIdx.x;
    if (e >= NNZ) return;
    atomicAdd(&cnt[row[e]], 1);
}

// ---------------------------------------------------------------------------
// CSR build step 2a: per-block sums of cnt (1024 elements / block)
// ---------------------------------------------------------------------------
__global__ void lgcn_scan_blocksums(const int* __restrict__ cnt,
                                    int* __restrict__ blockSum) {
    int b = blockIdx.x, t = threadIdx.x;
    int base = b * SCAN_ITEMS + t * 4;
    int s = 0;
#pragma unroll
    for (int k = 0; k < 4; ++k) {
        int i = base + k;
        if (i < N_NODES) s += cnt[i];
    }
    __shared__ int red[256];
    red[t] = s;
    __syncthreads();
    for (int off = 128; off > 0; off >>= 1) {
        if (t < off) red[t] += red[t + off];
        __syncthreads();
    }
    if (t == 0) blockSum[b] = red[0];
}

// ---------------------------------------------------------------------------
// CSR build step 2b: exclusive scan of block sums (single block)
// ---------------------------------------------------------------------------
__global__ void lgcn_scan_sums(const int* __restrict__ blockSum,
                               int* __restrict__ blockBase,
                               int* __restrict__ row_ptr) {
    int t = threadIdx.x;
    __shared__ int s[256];
    int v = (t < NUM_SCAN_BLOCKS) ? blockSum[t] : 0;
    s[t] = v;
    __syncthreads();
    for (int off = 1; off < 256; off <<= 1) {
        int x = (t >= off) ? s[t - off] : 0;
        __syncthreads();
        s[t] += x;
        __syncthreads();
    }
    if (t < NUM_SCAN_BLOCKS) blockBase[t] = s[t] - v;  // exclusive
    if (t == 0) row_ptr[N_NODES] = NNZ;
}

// ---------------------------------------------------------------------------
// CSR build step 2c: final exclusive scan -> row_ptr[0..N_NODES)
// ---------------------------------------------------------------------------
__global__ void lgcn_scan_final(const int* __restrict__ cnt,
                                const int* __restrict__ blockBase,
                                int* __restrict__ row_ptr) {
    int b = blockIdx.x, t = threadIdx.x;
    int base = b * SCAN_ITEMS + t * 4;
    int v[4];
    int tsum = 0;
#pragma unroll
    for (int k = 0; k < 4; ++k) {
        int i = base + k;
        v[k] = (i < N_NODES) ? cnt[i] : 0;
        tsum += v[k];
    }
    __shared__ int s[256];
    s[t] = tsum;
    __syncthreads();
    for (int off = 1; off < 256; off <<= 1) {
        int x = (t >= off) ? s[t - off] : 0;
        __syncthreads();
        s[t] += x;
        __syncthreads();
    }
    int p = blockBase[b] + (s[t] - tsum);  // exclusive prefix for this thread
#pragma unroll
    for (int k = 0; k < 4; ++k) {
        int i = base + k;
        if (i < N_NODES) row_ptr[i] = p;
        p += v[k];
    }
}

// ---------------------------------------------------------------------------
// CSR build step 3: scatter (col, val) into CSR order — interleaved int2,
// plain store (NT store measured as a regression in R4)
// ---------------------------------------------------------------------------
__global__ void lgcn_scatter(const int* __restrict__ row,
                             const int* __restrict__ col,
                             const float* __restrict__ vals,
                             const int* __restrict__ row_ptr,
                             int* __restrict__ cursor,
                             int2* __restrict__ csr_cv) {
    int e = blockIdx.x * blockDim.x + threadIdx.x;
    if (e >= NNZ) return;
    int r = row[e];
    int pos = row_ptr[r] + atomicAdd(&cursor[r], 1);
    csr_cv[pos] = make_int2(col[e], __float_as_int(vals[e]));
}

// ---------------------------------------------------------------------------
// SpMM, bf16 gather: one wave per row. Lanes = 8 edge-subgroups x 8 chunks.
// Each lane loads 16B = 8 bf16 of x[col]; a row is 128B = ONE cache line.
// fp32 accumulate; epilogue writes y as bf16 (next layer input) and folds
// fp32 y into acc: acc = (acc + y) * scale.
// ---------------------------------------------------------------------------
__global__ __launch_bounds__(256) void lgcn_spmm_bf16(
    const int* __restrict__ row_ptr,
    const int2* __restrict__ csr_cv,
    const uint4* __restrict__ xb,
    uint4* __restrict__ yb,
    float4* __restrict__ acc,
    float scale) {
    int gid = blockIdx.x * blockDim.x + threadIdx.x;
    int r = gid >> 6;
    if (r >= N_NODES) return;
    int lane = threadIdx.x & 63;
    int c = lane & 7;        // which 16B chunk (8 bf16) of the 64-dim row
    int sub = lane >> 3;     // edge subgroup 0..7

    int start = row_ptr[r];
    int end = row_ptr[r + 1];

    float a0[8] = {0.f, 0.f, 0.f, 0.f, 0.f, 0.f, 0.f, 0.f};
    float a1[8] = {0.f, 0.f, 0.f, 0.f, 0.f, 0.f, 0.f, 0.f};

    int e = start + sub;
    // main loop: 16 edges per wave iteration (2 per subgroup, independent)
    for (; e + 8 < end; e += 16) {
        int2 cv0 = csr_cv[e];
        int2 cv1 = csr_cv[e + 8];
        uint4 u0 = xb[cv0.x * 8 + c];
        uint4 u1 = xb[cv1.x * 8 + c];
        float v0 = __int_as_float(cv0.y);
        float v1 = __int_as_float(cv1.y);
        a0[0] += v0 * bflo(u0.x); a0[1] += v0 * bfhi(u0.x);
        a0[2] += v0 * bflo(u0.y); a0[3] += v0 * bfhi(u0.y);
        a0[4] += v0 * bflo(u0.z); a0[5] += v0 * bfhi(u0.z);
        a0[6] += v0 * bflo(u0.w); a0[7] += v0 * bfhi(u0.w);
        a1[0] += v1 * bflo(u1.x); a1[1] += v1 * bfhi(u1.x);
        a1[2] += v1 * bflo(u1.y); a1[3] += v1 * bfhi(u1.y);
        a1[4] += v1 * bflo(u1.z); a1[5] += v1 * bfhi(u1.z);
        a1[6] += v1 * bflo(u1.w); a1[7] += v1 * bfhi(u1.w);
    }
    // at most one edge left per subgroup
    if (e < end) {
        int2 cv = csr_cv[e];
        uint4 u = xb[cv.x * 8 + c];
        float v = __int_as_float(cv.y);
        a0[0] += v * bflo(u.x); a0[1] += v * bfhi(u.x);
        a0[2] += v * bflo(u.y); a0[3] += v * bfhi(u.y);
        a0[4] += v * bflo(u.z); a0[5] += v * bfhi(u.z);
        a0[6] += v * bflo(u.w); a0[7] += v * bfhi(u.w);
    }

    float a[8];
#pragma unroll
    for (int k = 0; k < 8; ++k) a[k] = a0[k] + a1[k];

    // reduce across the 8 edge subgroups (lanes differing in bits 3,4,5)
#pragma unroll
    for (int k = 0; k < 8; ++k) {
        a[k] += __shfl_xor(a[k], 8);
        a[k] += __shfl_xor(a[k], 16);
        a[k] += __shfl_xor(a[k], 32);
    }

    if (sub == 0) {
        // bf16 y for the next layer's gather
        uint4 p;
        p.x = f2bf(a[0]) | (f2bf(a[1]) << 16);
        p.y = f2bf(a[2]) | (f2bf(a[3]) << 16);
        p.z = f2bf(a[4]) | (f2bf(a[5]) << 16);
        p.w = f2bf(a[6]) | (f2bf(a[7]) << 16);
        yb[r * 8 + c] = p;
        // fp32 accumulator update (full-precision y folded in)
        int idx = r * 16 + c * 2;
        float4 o0 = acc[idx];
        float4 o1 = acc[idx + 1];
        o0.x = (o0.x + a[0]) * scale;
        o0.y = (o0.y + a[1]) * scale;
        o0.z = (o0.z + a[2]) * scale;
        o0.w = (o0.w + a[3]) * scale;
        o1.x = (o1.x + a[4]) * scale;
        o1.y = (o1.y + a[5]) * scale;
        o1.z = (o1.z + a[6]) * scale;
        o1.w = (o1.w + a[7]) * scale;
        acc[idx] = o0;
        acc[idx + 1] = o1;
    }
}

extern "C" void kernel_launch(void* const* d_in, const int* in_sizes, int n_in,
                              void* d_out, int out_size, void* d_ws, size_t ws_size,
                              hipStream_t stream) {
    const float* user_emb = (const float*)d_in[0];
    const float* item_emb = (const float*)d_in[1];
    const int*   adj_row  = (const int*)d_in[2];
    const int*   adj_col  = (const int*)d_in[3];
    const float* adj_vals = (const float*)d_in[4];
    float* out = (float*)d_out;

    // workspace layout (~78 MB total)
    uint4* xb_a  = (uint4*)d_ws;                               // 19.2 MB bf16
    uint4* xb_b  = xb_a + (size_t)N_NODES * 8;                 // 19.2 MB bf16
    int*   cnt     = (int*)(xb_b + (size_t)N_NODES * 8);       // 600 KB
    int*   row_ptr = cnt + N_NODES;                            // 600 KB
    int*   blockSum  = row_ptr + (N_NODES + 1);                // 1 KB
    int*   blockBase = blockSum + 256;                         // 1 KB
    int2*  csr_cv  = (int2*)(blockBase + 256);                 // 38.4 MB

    // init: xb_a = bf16(concat(user,item)); out (acc) = fp32 concat
    {
        int threads = 256;
        int blocks = (N_NODES * 8 + threads - 1) / threads;
        lgcn_init<<<blocks, threads, 0, stream>>>(
            (const float4*)user_emb, (const float4*)item_emb,
            xb_a, (float4*)out);
    }

    // ---- CSR build ----
    hipMemsetAsync(cnt, 0, (size_t)N_NODES * sizeof(int), stream);
    {
        int threads = 256;
        int blocks = (NNZ + threads - 1) / threads;
        lgcn_hist<<<blocks, threads, 0, stream>>>(adj_row, cnt);
    }
    lgcn_scan_blocksums<<<NUM_SCAN_BLOCKS, 256, 0, stream>>>(cnt, blockSum);
    lgcn_scan_sums<<<1, 256, 0, stream>>>(blockSum, blockBase, row_ptr);
    lgcn_scan_final<<<NUM_SCAN_BLOCKS, 256, 0, stream>>>(cnt, blockBase, row_ptr);
    hipMemsetAsync(cnt, 0, (size_t)N_NODES * sizeof(int), stream);  // reuse as cursor
    {
        int threads = 256;
        int blocks = (NNZ + threads - 1) / threads;
        lgcn_scatter<<<blocks, threads, 0, stream>>>(
            adj_row, adj_col, adj_vals, row_ptr, cnt, csr_cv);
    }

    // ---- 3 propagation layers (bf16-gather SpMM, fused fp32 acc update) ----
    const int spmm_block = 256;                       // 4 waves = 4 rows / block
    const int spmm_grid = (N_NODES * 64 + spmm_block - 1) / spmm_block;
    for (int layer = 0; layer < 3; ++layer) {
        float scale = (layer == 2) ? 0.25f : 1.0f;
        lgcn_spmm_bf16<<<spmm_grid, spmm_block, 0, stream>>>(
            row_ptr, csr_cv, xb_a, xb_b, (float4*)out, scale);
        uint4* t = xb_a; xb_a = xb_b; xb_b = t;
    }
}